// Round 4
// baseline (823.892 us; speedup 1.0000x reference)
//
#include <hip/hip_runtime.h>
#include <math.h>

// DualAttention: B=64, S=2048, H=512, F=128, fp32 in/out.
#define NB 64
#define NS 2048
#define NH 512
#define NF 128
#define BS (NB * NS)

typedef __attribute__((ext_vector_type(8))) short bf16x8;   // 8 bf16 = 4 VGPRs
typedef __attribute__((ext_vector_type(4))) float f32x4;    // MFMA C/D

__device__ inline unsigned short f2bf(float x) {            // fp32->bf16 RNE
  union { float f; unsigned u; } v; v.f = x;
  unsigned r = v.u + 0x7fff + ((v.u >> 16) & 1);
  return (unsigned short)(r >> 16);
}
__device__ inline float bf2f(unsigned short b) {
  union { float f; unsigned u; } v; v.u = ((unsigned)b) << 16; return v.f;
}
__device__ inline float fast_tanh(float x) {
  float e = __expf(2.f * x);
  return 1.f - 2.f / (e + 1.f);
}
__device__ inline void split4(float4 p, ushort4& hv, ushort4& lv) {
  hv = make_ushort4(f2bf(p.x), f2bf(p.y), f2bf(p.z), f2bf(p.w));
  lv = make_ushort4(f2bf(p.x - bf2f(hv.x)), f2bf(p.y - bf2f(hv.y)),
                    f2bf(p.z - bf2f(hv.z)), f2bf(p.w - bf2f(hv.w)));
}

// ---------------------------------------------------------------------------
// Pack W [K,512] fp32 -> MFMA B-frag layout, hi/lo INTERLEAVED per fragment:
// frag f = (kt*32+nt)*64+lane holds hi bf16x8 at ush f*16, lo at f*16+8
// (adjacent in one cache line). k = kt*32+(lane>>4)*8+j, n = nt*16+(lane&15).
// ---------------------------------------------------------------------------
__global__ __launch_bounds__(256) void pack_w_kernel(
    const float* __restrict__ W, unsigned short* __restrict__ out) {
  const int tid = blockIdx.x * 256 + threadIdx.x;
  const int j = tid & 7, l = (tid >> 3) & 63, nt = (tid >> 9) & 31, kt = tid >> 14;
  const int k = kt * 32 + (l >> 4) * 8 + j;
  const int n = nt * 16 + (l & 15);
  const float x = W[k * NH + n];
  const unsigned short h = f2bf(x);
  const int base = ((tid >> 3) << 4) + j;   // f*16 + j
  out[base] = h;
  out[base + 8] = f2bf(x - bf2f(h));
}

// ---------------------------------------------------------------------------
// Fused score GEMM, split-bf16 MFMA (3 products ~ fp32 precision):
//   spart[cgp][r] = sum_{n in half} tanh((A[r,:] @ W[:,n]) + bias[n]) * pin[b,n]
// Block: 256 thr = 4 waves = (rg in {0,1}) x (cg in {0,1}); M=64 rows, N=256
// (cols [cgp*256, cgp*256+256)). Per wave mt=2 -> acc 64 regs -> 3 waves/SIMD
// (R3 was 2: 128-reg acc capped occupancy; that was the latency bottleneck).
// W traffic per MFMA unchanged (M=64 per W-read = ~42 B/cyc/CU < L2 ceiling).
// A double-buffered in LDS as split bf16 (row stride 40 ush -> b128-aligned).
// ---------------------------------------------------------------------------
template <int K>
__global__ __launch_bounds__(256, 3) void score_mfma(
    const float* __restrict__ A, const unsigned short* __restrict__ Wint,
    const float* __restrict__ bias, const float* __restrict__ pin,
    float* __restrict__ spart) {
  constexpr int KT = K / 32;
  __shared__ __align__(16) unsigned short lAhi[2][64 * 40];
  __shared__ __align__(16) unsigned short lAlo[2][64 * 40];
  __shared__ float red[4 * 32];
  const int t = threadIdx.x;
  const int wave = t >> 6, lane = t & 63;
  const int cg = wave & 1, rg = wave >> 1;
  const int strip = blockIdx.x >> 1, cgp = blockIdx.x & 1;
  const int row0 = strip * 64;
  const int b = row0 >> 11;           // row0 / S
  const int nb = cgp * 16 + cg * 8;   // first ntile of this wave

  f32x4 acc[2][8];
#pragma unroll
  for (int mt = 0; mt < 2; ++mt)
#pragma unroll
    for (int nt = 0; nt < 8; ++nt) acc[mt][nt] = (f32x4)0.f;

  // staging: thread t loads float4 at rows {lr, lr+32}, col lc
  const int lr = t >> 3, lc = (t & 7) * 4;
  const float* Ab0 = A + (size_t)(row0 + lr) * K + lc;
  const float* Ab1 = Ab0 + (size_t)32 * K;
  const int fr = lane & 15, fq = lane >> 4;
  // W fragment pointer (bf16x8 units): frag f = (kt*32 + nb + nt)*64 + lane,
  // hi at 2f, lo at 2f+1; advances 4096 units per kt.
  const bf16x8* wp = (const bf16x8*)Wint + ((size_t)(nb * 64 + lane) << 1);

  {  // prologue: stage kt=0 into buffer 0
    ushort4 hv, lv;
    split4(*(const float4*)Ab0, hv, lv);
    *(ushort4*)&lAhi[0][lr * 40 + lc] = hv;
    *(ushort4*)&lAlo[0][lr * 40 + lc] = lv;
    split4(*(const float4*)Ab1, hv, lv);
    *(ushort4*)&lAhi[0][(lr + 32) * 40 + lc] = hv;
    *(ushort4*)&lAlo[0][(lr + 32) * 40 + lc] = lv;
  }
  __syncthreads();

  for (int kt = 0; kt < KT; ++kt) {
    const int cur = kt & 1;
    float4 q0, q1;
    if (kt < KT - 1) {                 // global prefetch: whole MFMA block to land
      q0 = *(const float4*)(Ab0 + (kt + 1) * 32);
      q1 = *(const float4*)(Ab1 + (kt + 1) * 32);
    }
    bf16x8 ah[2], al[2];
#pragma unroll
    for (int mt = 0; mt < 2; ++mt) {
      const int ra = (rg * 32 + mt * 16 + fr) * 40 + fq * 8;
      ah[mt] = *(const bf16x8*)&lAhi[cur][ra];
      al[mt] = *(const bf16x8*)&lAlo[cur][ra];
    }
#pragma unroll
    for (int nt = 0; nt < 8; ++nt) {
      const bf16x8 wh = wp[nt * 128];
      const bf16x8 wl = wp[nt * 128 + 1];
#pragma unroll
      for (int mt = 0; mt < 2; ++mt) {
        acc[mt][nt] = __builtin_amdgcn_mfma_f32_16x16x32_bf16(ah[mt], wh, acc[mt][nt], 0, 0, 0);
        acc[mt][nt] = __builtin_amdgcn_mfma_f32_16x16x32_bf16(ah[mt], wl, acc[mt][nt], 0, 0, 0);
        acc[mt][nt] = __builtin_amdgcn_mfma_f32_16x16x32_bf16(al[mt], wh, acc[mt][nt], 0, 0, 0);
      }
    }
    wp += 4096;
    if (kt < KT - 1) {                 // stage next tile into other buffer
      const int nxt = cur ^ 1;
      ushort4 hv, lv;
      split4(q0, hv, lv);
      *(ushort4*)&lAhi[nxt][lr * 40 + lc] = hv;
      *(ushort4*)&lAlo[nxt][lr * 40 + lc] = lv;
      split4(q1, hv, lv);
      *(ushort4*)&lAhi[nxt][(lr + 32) * 40 + lc] = hv;
      *(ushort4*)&lAlo[nxt][(lr + 32) * 40 + lc] = lv;
    }
    __syncthreads();
  }

  // Epilogue: tanh + weighted column-reduce over this wave's 128 cols.
  // C layout: col = (nb+nt)*16 + fr ; row = rg*32 + mt*16 + fq*4 + r.
  float ps[2][4];
#pragma unroll
  for (int mt = 0; mt < 2; ++mt)
#pragma unroll
    for (int r = 0; r < 4; ++r) ps[mt][r] = 0.f;
#pragma unroll
  for (int nt = 0; nt < 8; ++nt) {
    const int col = (nb + nt) * 16 + fr;
    const float bi = bias[col], pi = pin[b * NH + col];
#pragma unroll
    for (int mt = 0; mt < 2; ++mt)
#pragma unroll
      for (int r = 0; r < 4; ++r)
        ps[mt][r] += fast_tanh(acc[mt][nt][r] + bi) * pi;
  }
#pragma unroll
  for (int m = 8; m; m >>= 1)
#pragma unroll
    for (int mt = 0; mt < 2; ++mt)
#pragma unroll
      for (int r = 0; r < 4; ++r) ps[mt][r] += __shfl_xor(ps[mt][r], m);
  if (fr == 0)
#pragma unroll
    for (int mt = 0; mt < 2; ++mt)
#pragma unroll
      for (int r = 0; r < 4; ++r) red[wave * 32 + mt * 16 + fq * 4 + r] = ps[mt][r];
  __syncthreads();
  if (t < 64)  // row i of strip: sum the 2 col-groups of rg = i>>5
    spart[(size_t)cgp * BS + row0 + t] =
        red[((t >> 5) * 2) * 32 + (t & 31)] + red[((t >> 5) * 2 + 1) * 32 + (t & 31)];
}

// ---------------------------------------------------------------------------
// proj_in: tanh(input @ W_{a,b} + b_{a,b}); grid (B,4).
// ---------------------------------------------------------------------------
__global__ __launch_bounds__(256) void proj_in_kernel(
    const float* __restrict__ input,
    const float* __restrict__ W_a, const float* __restrict__ b_a,
    const float* __restrict__ W_b, const float* __restrict__ b_b,
    float* __restrict__ pa, float* __restrict__ pb) {
  __shared__ float sin_[NH];
  const int b = blockIdx.x, part = blockIdx.y, t = threadIdx.x;
  const float* W  = (part < 2) ? W_a : W_b;
  const float* bi = (part < 2) ? b_a : b_b;
  float* out      = (part < 2) ? pa : pb;
  const int h = t + (part & 1) * 256;
  sin_[t] = input[b * NH + t];
  sin_[t + 256] = input[b * NH + t + 256];
  __syncthreads();
  float acc = 0.f;
  for (int k = 0; k < NH; ++k) acc = fmaf(sin_[k], W[k * NH + h], acc);
  out[b * NH + h] = tanhf(acc + bi[h]);
}

// ---------------------------------------------------------------------------
// gamma = softmax_S(sa0+sa1+sb0+sb1)  (partials from the N-split score blocks;
// softmax(a)*softmax(b) L1-renormalized == softmax(a+b))
// ---------------------------------------------------------------------------
__global__ __launch_bounds__(256) void gamma_kernel(
    const float* __restrict__ sa, const float* __restrict__ sb,
    float* __restrict__ gamma) {
  const int b = blockIdx.x, t = threadIdx.x;
  __shared__ float swp[4];
  float v[8];
  float mx = -1e30f;
#pragma unroll
  for (int i = 0; i < 8; ++i) {
    const int s = b * NS + t + i * 256;
    v[i] = sa[s] + sa[BS + s] + sb[s] + sb[BS + s];
    mx = fmaxf(mx, v[i]);
  }
  const int wave = t >> 6, lane = t & 63;
#pragma unroll
  for (int off = 32; off; off >>= 1) mx = fmaxf(mx, __shfl_down(mx, off));
  if (lane == 0) swp[wave] = mx;
  __syncthreads();
  mx = fmaxf(fmaxf(swp[0], swp[1]), fmaxf(swp[2], swp[3]));
  __syncthreads();
  float sum = 0.f;
#pragma unroll
  for (int i = 0; i < 8; ++i) {
    v[i] = __expf(v[i] - mx);
    sum += v[i];
  }
#pragma unroll
  for (int off = 32; off; off >>= 1) sum += __shfl_down(sum, off);
  if (lane == 0) swp[wave] = sum;
  __syncthreads();
  const float inv = 1.f / (swp[0] + swp[1] + swp[2] + swp[3]);
#pragma unroll
  for (int i = 0; i < 8; ++i) gamma[b * NS + t + i * 256] = v[i] * inv;
}

// ---------------------------------------------------------------------------
// wctx partials: grid (B,8); float4 columns; wcp has 16 chunks per batch.
// ---------------------------------------------------------------------------
__global__ __launch_bounds__(256) void wctx_kernel(
    const float* __restrict__ ctx, const float* __restrict__ gamma,
    float* __restrict__ wcp) {
  const int b = blockIdx.x, ch = blockIdx.y, t = threadIdx.x;
  __shared__ float g[256];
  const int s0 = ch * 256;
  g[t] = gamma[b * NS + s0 + t];
  __syncthreads();
  const int sh = t >> 7, h4 = (t & 127) * 4;
  float4 acc = make_float4(0.f, 0.f, 0.f, 0.f);
  const float* base = ctx + (size_t)(b * NS + s0 + sh * 128) * NH + h4;
#pragma unroll 4
  for (int s = 0; s < 128; ++s) {
    const float gs = g[sh * 128 + s];
    const float4 c = *(const float4*)(base + (size_t)s * NH);
    acc.x = fmaf(gs, c.x, acc.x);
    acc.y = fmaf(gs, c.y, acc.y);
    acc.z = fmaf(gs, c.z, acc.z);
    acc.w = fmaf(gs, c.w, acc.w);
  }
  *(float4*)&wcp[(size_t)(b * 16 + ch * 2 + sh) * NH + h4] = acc;
}

// ---------------------------------------------------------------------------
// out: reduce 16 wcp chunks -> wc; h_tilde = tanh([wc,input] @ W_out). grid (B,2).
// ---------------------------------------------------------------------------
__global__ __launch_bounds__(256) void out_kernel(
    const float* __restrict__ wcp, const float* __restrict__ input,
    const float* __restrict__ W_out, float* __restrict__ out) {
  __shared__ float cat[2 * NH];
  const int b = blockIdx.x, half = blockIdx.y, t = threadIdx.x;
  for (int i = t; i < NH; i += 256) {
    float s = 0.f;
#pragma unroll
    for (int c = 0; c < 16; ++c) s += wcp[(size_t)(b * 16 + c) * NH + i];
    cat[i] = s;
    cat[NH + i] = input[b * NH + i];
  }
  __syncthreads();
  const int o = half * 256 + t;
  float acc = 0.f;
  for (int k = 0; k < 2 * NH; ++k) acc = fmaf(cat[k], W_out[(size_t)k * NH + o], acc);
  out[b * NH + o] = tanhf(acc);
}

// ---------------------------------------------------------------------------
extern "C" void kernel_launch(void* const* d_in, const int* in_sizes, int n_in,
                              void* d_out, int out_size, void* d_ws, size_t ws_size,
                              hipStream_t stream) {
  const float* input   = (const float*)d_in[0];
  const float* context = (const float*)d_in[1];
  const float* input_z = (const float*)d_in[2];
  const float* W_enc   = (const float*)d_in[3];
  const float* b_enc   = (const float*)d_in[4];
  const float* W_a     = (const float*)d_in[5];
  const float* b_a     = (const float*)d_in[6];
  const float* W_b     = (const float*)d_in[7];
  const float* b_b     = (const float*)d_in[8];
  const float* W_z     = (const float*)d_in[9];
  const float* b_z     = (const float*)d_in[10];
  const float* W_out   = (const float*)d_in[11];

  float* out = (float*)d_out;          // [0,32768): h_tilde, then gamma
  float* ws  = (float*)d_ws;
  float* pa  = ws;                     // 32768
  float* pb  = ws + 32768;             // 32768
  float* sa  = ws + 65536;             // 2*B*S = 262144 (two N-half partials)
  float* sb  = ws + 327680;            // 2*B*S = 262144
  float* wcp = ws + 589824;            // 64*16*512 = 524288
  unsigned short* WintE = (unsigned short*)(ws + 1114112);  // 512*512*2 ush = 1 MB
  unsigned short* WintZ = (unsigned short*)(ws + 1376256);  // 128*512*2 ush = 256 KB
  float* gamma = out + NB * NH;

  hipLaunchKernelGGL(pack_w_kernel, dim3(NH * NH / 256), dim3(256), 0, stream,
                     W_enc, WintE);
  hipLaunchKernelGGL(pack_w_kernel, dim3(NF * NH / 256), dim3(256), 0, stream,
                     W_z, WintZ);
  hipLaunchKernelGGL(proj_in_kernel, dim3(NB, 4), dim3(256), 0, stream,
                     input, W_a, b_a, W_b, b_b, pa, pb);
  hipLaunchKernelGGL(score_mfma<NH>, dim3(BS / 64 * 2), dim3(256), 0, stream,
                     context, WintE, b_enc, pa, sa);
  hipLaunchKernelGGL(score_mfma<NF>, dim3(BS / 64 * 2), dim3(256), 0, stream,
                     input_z, WintZ, b_z, pb, sb);
  hipLaunchKernelGGL(gamma_kernel, dim3(NB), dim3(256), 0, stream, sa, sb, gamma);
  hipLaunchKernelGGL(wctx_kernel, dim3(NB, 8), dim3(256), 0, stream,
                     context, gamma, wcp);
  hipLaunchKernelGGL(out_kernel, dim3(NB, 2), dim3(256), 0, stream,
                     wcp, input, W_out, out);
}

// Round 5
// 648.022 us; speedup vs baseline: 1.2714x; 1.2714x over previous
//
#include <hip/hip_runtime.h>
#include <math.h>

// DualAttention: B=64, S=2048, H=512, F=128, fp32 in/out.
#define NB 64
#define NS 2048
#define NH 512
#define NF 128
#define BS (NB * NS)

typedef __attribute__((ext_vector_type(8))) _Float16 f16x8;  // 4 VGPRs (MFMA A/B)
typedef __attribute__((ext_vector_type(4))) _Float16 f16x4;  // 8 B LDS store
typedef __attribute__((ext_vector_type(4))) float f32x4;     // MFMA C/D

__device__ inline float fast_tanh(float x) {
  float e = __expf(2.f * x);
  return 1.f - 2.f / (e + 1.f);
}
// fp32 -> fp16 hi + fp16 lo (2-term split, exact to ~2^-22 rel)
__device__ inline void split4h(float4 p, f16x4& hv, f16x4& lv) {
  hv.x = (_Float16)p.x; hv.y = (_Float16)p.y; hv.z = (_Float16)p.z; hv.w = (_Float16)p.w;
  lv.x = (_Float16)(p.x - (float)hv.x);
  lv.y = (_Float16)(p.y - (float)hv.y);
  lv.z = (_Float16)(p.z - (float)hv.z);
  lv.w = (_Float16)(p.w - (float)hv.w);
}

// ---------------------------------------------------------------------------
// Pack W [K,512] fp32 -> MFMA B-frag layout, SINGLE fp16 plane.
// frag f = kt*32+nt (one per 16x16x32 B tile); element f*64*8 + lane*8 + j
// holds W[k,n], k = kt*32+(lane>>4)*8+j, n = nt*16+(lane&15).
// ---------------------------------------------------------------------------
__global__ __launch_bounds__(256) void pack_w_kernel(
    const float* __restrict__ W, _Float16* __restrict__ out) {
  const int tid = blockIdx.x * 256 + threadIdx.x;
  const int j = tid & 7, l = (tid >> 3) & 63, nt = (tid >> 9) & 31, kt = tid >> 14;
  const int k = kt * 32 + (l >> 4) * 8 + j;
  const int n = nt * 16 + (l & 15);
  out[tid] = (_Float16)W[k * NH + n];
}

// ---------------------------------------------------------------------------
// Fused score GEMM, asymmetric fp16 split (A: hi+lo fp16, W: single fp16;
// 2 MFMA products ~ fp32 precision — W fp16 rounding gives ~1e-4 proj err):
//   score[r] = sum_n tanh((A[r,:] @ W[:,n]) + bias[n]) * pin[b,n]
// Block: 256 thr = 4 waves; M=64 rows, N=512; wave w owns cols [w*128,w*128+128),
// mt=4, nt=8, acc 128 regs -> 2 waves/SIMD (structural).
// W software-pipelined one fragment ahead (covers ~200cyc L2 latency with the
// previous group's 8 MFMAs x 2 waves/SIMD). A double-buffered in LDS, 1
// barrier/kt; A global prefetch issued a full MFMA block ahead.
// ---------------------------------------------------------------------------
template <int K>
__global__ __launch_bounds__(256, 2) void score_mfma(
    const float* __restrict__ A, const _Float16* __restrict__ Wp,
    const float* __restrict__ bias, const float* __restrict__ pin,
    float* __restrict__ score) {
  constexpr int KT = K / 32;
  __shared__ __align__(16) _Float16 lAhi[2][64 * 40];  // row stride 80 B (16B mult)
  __shared__ __align__(16) _Float16 lAlo[2][64 * 40];
  __shared__ float red[4 * 64];
  const int t = threadIdx.x;
  const int wave = t >> 6, lane = t & 63;
  const int row0 = blockIdx.x * 64;
  const int b = row0 >> 11;  // row0 / S
  const int nb = wave * 8;   // first ntile of this wave

  f32x4 acc[4][8];
#pragma unroll
  for (int mt = 0; mt < 4; ++mt)
#pragma unroll
    for (int nt = 0; nt < 8; ++nt) acc[mt][nt] = (f32x4)0.f;

  // staging: thread t loads float4 at rows {lr, lr+32}, col lc
  const int lr = t >> 3, lc = (t & 7) * 4;
  const float* Ab0 = A + (size_t)(row0 + lr) * K + lc;
  const float* Ab1 = Ab0 + (size_t)32 * K;
  const int fr = lane & 15, fq = lane >> 4;

  // W fragment stream (f16x8 = 16B units): frag f at unit f*64 + lane.
  const f16x8* wp = (const f16x8*)Wp + (size_t)nb * 64 + lane;
  f16x8 wcur = *wp;

  {  // prologue: stage kt=0 into buffer 0
    f16x4 hv, lv;
    split4h(*(const float4*)Ab0, hv, lv);
    *(f16x4*)&lAhi[0][lr * 40 + lc] = hv;
    *(f16x4*)&lAlo[0][lr * 40 + lc] = lv;
    split4h(*(const float4*)Ab1, hv, lv);
    *(f16x4*)&lAhi[0][(lr + 32) * 40 + lc] = hv;
    *(f16x4*)&lAlo[0][(lr + 32) * 40 + lc] = lv;
  }
  __syncthreads();

  for (int kt = 0; kt < KT; ++kt) {
    const int cur = kt & 1;
    float4 q0, q1;
    if (kt < KT - 1) {                 // global A prefetch (HBM, ~1 kt to land)
      q0 = *(const float4*)(Ab0 + (kt + 1) * 32);
      q1 = *(const float4*)(Ab1 + (kt + 1) * 32);
    }
    f16x8 ah[4], al[4];
#pragma unroll
    for (int mt = 0; mt < 4; ++mt) {
      const int ra = (mt * 16 + fr) * 40 + fq * 8;
      ah[mt] = *(const f16x8*)&lAhi[cur][ra];
      al[mt] = *(const f16x8*)&lAlo[cur][ra];
    }
#pragma unroll
    for (int nt = 0; nt < 8; ++nt) {
      // prefetch next W fragment: +1 frag within kt, +25 frags at kt boundary
      const int adv = (nt < 7) ? 64 : ((kt < KT - 1) ? 25 * 64 : 0);
      const f16x8 wnxt = wp[adv];
#pragma unroll
      for (int mt = 0; mt < 4; ++mt) {
        acc[mt][nt] = __builtin_amdgcn_mfma_f32_16x16x32_f16(ah[mt], wcur, acc[mt][nt], 0, 0, 0);
        acc[mt][nt] = __builtin_amdgcn_mfma_f32_16x16x32_f16(al[mt], wcur, acc[mt][nt], 0, 0, 0);
      }
      wcur = wnxt;
      wp += adv;
    }
    if (kt < KT - 1) {                 // stage next A tile into other buffer
      const int nxt = cur ^ 1;
      f16x4 hv, lv;
      split4h(q0, hv, lv);
      *(f16x4*)&lAhi[nxt][lr * 40 + lc] = hv;
      *(f16x4*)&lAlo[nxt][lr * 40 + lc] = lv;
      split4h(q1, hv, lv);
      *(f16x4*)&lAhi[nxt][(lr + 32) * 40 + lc] = hv;
      *(f16x4*)&lAlo[nxt][(lr + 32) * 40 + lc] = lv;
    }
    __syncthreads();
  }

  // Epilogue: tanh + weighted column-reduce over this wave's 128 cols.
  // C layout: col = (nb+nt)*16 + fr ; row = mt*16 + fq*4 + r.
  float ps[4][4];
#pragma unroll
  for (int mt = 0; mt < 4; ++mt)
#pragma unroll
    for (int r = 0; r < 4; ++r) ps[mt][r] = 0.f;
#pragma unroll
  for (int nt = 0; nt < 8; ++nt) {
    const int col = (nb + nt) * 16 + fr;
    const float bi = bias[col], pi = pin[b * NH + col];
#pragma unroll
    for (int mt = 0; mt < 4; ++mt)
#pragma unroll
      for (int r = 0; r < 4; ++r)
        ps[mt][r] += fast_tanh(acc[mt][nt][r] + bi) * pi;
  }
#pragma unroll
  for (int m = 8; m; m >>= 1)
#pragma unroll
    for (int mt = 0; mt < 4; ++mt)
#pragma unroll
      for (int r = 0; r < 4; ++r) ps[mt][r] += __shfl_xor(ps[mt][r], m);
  if (fr == 0)
#pragma unroll
    for (int mt = 0; mt < 4; ++mt)
#pragma unroll
      for (int r = 0; r < 4; ++r) red[wave * 64 + mt * 16 + fq * 4 + r] = ps[mt][r];
  __syncthreads();
  if (t < 64) score[row0 + t] = red[t] + red[64 + t] + red[128 + t] + red[192 + t];
}

// ---------------------------------------------------------------------------
// proj_in: tanh(input @ W_{a,b} + b_{a,b}); grid (B,4).
// ---------------------------------------------------------------------------
__global__ __launch_bounds__(256) void proj_in_kernel(
    const float* __restrict__ input,
    const float* __restrict__ W_a, const float* __restrict__ b_a,
    const float* __restrict__ W_b, const float* __restrict__ b_b,
    float* __restrict__ pa, float* __restrict__ pb) {
  __shared__ float sin_[NH];
  const int b = blockIdx.x, part = blockIdx.y, t = threadIdx.x;
  const float* W  = (part < 2) ? W_a : W_b;
  const float* bi = (part < 2) ? b_a : b_b;
  float* out      = (part < 2) ? pa : pb;
  const int h = t + (part & 1) * 256;
  sin_[t] = input[b * NH + t];
  sin_[t + 256] = input[b * NH + t + 256];
  __syncthreads();
  float acc = 0.f;
  for (int k = 0; k < NH; ++k) acc = fmaf(sin_[k], W[k * NH + h], acc);
  out[b * NH + h] = tanhf(acc + bi[h]);
}

// ---------------------------------------------------------------------------
// gamma = softmax_S(score_a + score_b)
// ---------------------------------------------------------------------------
__global__ __launch_bounds__(256) void gamma_kernel(
    const float* __restrict__ sa, const float* __restrict__ sb,
    float* __restrict__ gamma) {
  const int b = blockIdx.x, t = threadIdx.x;
  __shared__ float swp[4];
  float v[8];
  float mx = -1e30f;
#pragma unroll
  for (int i = 0; i < 8; ++i) {
    const int s = b * NS + t + i * 256;
    v[i] = sa[s] + sb[s];
    mx = fmaxf(mx, v[i]);
  }
  const int wave = t >> 6, lane = t & 63;
#pragma unroll
  for (int off = 32; off; off >>= 1) mx = fmaxf(mx, __shfl_down(mx, off));
  if (lane == 0) swp[wave] = mx;
  __syncthreads();
  mx = fmaxf(fmaxf(swp[0], swp[1]), fmaxf(swp[2], swp[3]));
  __syncthreads();
  float sum = 0.f;
#pragma unroll
  for (int i = 0; i < 8; ++i) {
    v[i] = __expf(v[i] - mx);
    sum += v[i];
  }
#pragma unroll
  for (int off = 32; off; off >>= 1) sum += __shfl_down(sum, off);
  if (lane == 0) swp[wave] = sum;
  __syncthreads();
  const float inv = 1.f / (swp[0] + swp[1] + swp[2] + swp[3]);
#pragma unroll
  for (int i = 0; i < 8; ++i) gamma[b * NS + t + i * 256] = v[i] * inv;
}

// ---------------------------------------------------------------------------
// wctx partials: grid (B,8); float4 columns; wcp has 16 chunks per batch.
// ---------------------------------------------------------------------------
__global__ __launch_bounds__(256) void wctx_kernel(
    const float* __restrict__ ctx, const float* __restrict__ gamma,
    float* __restrict__ wcp) {
  const int b = blockIdx.x, ch = blockIdx.y, t = threadIdx.x;
  __shared__ float g[256];
  const int s0 = ch * 256;
  g[t] = gamma[b * NS + s0 + t];
  __syncthreads();
  const int sh = t >> 7, h4 = (t & 127) * 4;
  float4 acc = make_float4(0.f, 0.f, 0.f, 0.f);
  const float* base = ctx + (size_t)(b * NS + s0 + sh * 128) * NH + h4;
#pragma unroll 4
  for (int s = 0; s < 128; ++s) {
    const float gs = g[sh * 128 + s];
    const float4 c = *(const float4*)(base + (size_t)s * NH);
    acc.x = fmaf(gs, c.x, acc.x);
    acc.y = fmaf(gs, c.y, acc.y);
    acc.z = fmaf(gs, c.z, acc.z);
    acc.w = fmaf(gs, c.w, acc.w);
  }
  *(float4*)&wcp[(size_t)(b * 16 + ch * 2 + sh) * NH + h4] = acc;
}

// ---------------------------------------------------------------------------
// out: reduce 16 wcp chunks -> wc; h_tilde = tanh([wc,input] @ W_out). grid (B,2).
// ---------------------------------------------------------------------------
__global__ __launch_bounds__(256) void out_kernel(
    const float* __restrict__ wcp, const float* __restrict__ input,
    const float* __restrict__ W_out, float* __restrict__ out) {
  __shared__ float cat[2 * NH];
  const int b = blockIdx.x, half = blockIdx.y, t = threadIdx.x;
  for (int i = t; i < NH; i += 256) {
    float s = 0.f;
#pragma unroll
    for (int c = 0; c < 16; ++c) s += wcp[(size_t)(b * 16 + c) * NH + i];
    cat[i] = s;
    cat[NH + i] = input[b * NH + i];
  }
  __syncthreads();
  const int o = half * 256 + t;
  float acc = 0.f;
  for (int k = 0; k < 2 * NH; ++k) acc = fmaf(cat[k], W_out[(size_t)k * NH + o], acc);
  out[b * NH + o] = tanhf(acc);
}

// ---------------------------------------------------------------------------
extern "C" void kernel_launch(void* const* d_in, const int* in_sizes, int n_in,
                              void* d_out, int out_size, void* d_ws, size_t ws_size,
                              hipStream_t stream) {
  const float* input   = (const float*)d_in[0];
  const float* context = (const float*)d_in[1];
  const float* input_z = (const float*)d_in[2];
  const float* W_enc   = (const float*)d_in[3];
  const float* b_enc   = (const float*)d_in[4];
  const float* W_a     = (const float*)d_in[5];
  const float* b_a     = (const float*)d_in[6];
  const float* W_b     = (const float*)d_in[7];
  const float* b_b     = (const float*)d_in[8];
  const float* W_z     = (const float*)d_in[9];
  const float* b_z     = (const float*)d_in[10];
  const float* W_out   = (const float*)d_in[11];

  float* out = (float*)d_out;          // [0,32768): h_tilde, then gamma
  float* ws  = (float*)d_ws;
  float* pa  = ws;                     // 32768
  float* pb  = ws + 32768;             // 32768
  float* sa  = ws + 65536;             // B*S = 131072
  float* sb  = ws + 196608;            // B*S = 131072
  float* wcp = ws + 327680;            // 64*16*512 = 524288
  _Float16* WpE = (_Float16*)(ws + 851968);   // 512*512 f16 = 512 KB
  _Float16* WpZ = (_Float16*)(ws + 983040);   // 128*512 f16 = 128 KB
  float* gamma = out + NB * NH;

  hipLaunchKernelGGL(pack_w_kernel, dim3(NH * NH / 256), dim3(256), 0, stream,
                     W_enc, WpE);
  hipLaunchKernelGGL(pack_w_kernel, dim3(NF * NH / 256), dim3(256), 0, stream,
                     W_z, WpZ);
  hipLaunchKernelGGL(proj_in_kernel, dim3(NB, 4), dim3(256), 0, stream,
                     input, W_a, b_a, W_b, b_b, pa, pb);
  hipLaunchKernelGGL(score_mfma<NH>, dim3(BS / 64), dim3(256), 0, stream,
                     context, WpE, b_enc, pa, sa);
  hipLaunchKernelGGL(score_mfma<NF>, dim3(BS / 64), dim3(256), 0, stream,
                     input_z, WpZ, b_z, pb, sb);
  hipLaunchKernelGGL(gamma_kernel, dim3(NB), dim3(256), 0, stream, sa, sb, gamma);
  hipLaunchKernelGGL(wctx_kernel, dim3(NB, 8), dim3(256), 0, stream,
                     context, gamma, wcp);
  hipLaunchKernelGGL(out_kernel, dim3(NB, 2), dim3(256), 0, stream,
                     wcp, input, W_out, out);
}